// Round 7
// baseline (216.310 us; speedup 1.0000x reference)
//
#include <hip/hip_runtime.h>
#include <stdint.h>

// Problem constants
#define BATCH 32
#define LLEN  36864
#define CCH   16
#define DOUT  512
#define KW    24
#define LOUT  1536            // LLEN / KW
#define MROWS (BATCH * LOUT)  // 49152 windows
#define CK    384             // CCH * KW (inner dot length)
#define TWOK  48

typedef float fx4 __attribute__((ext_vector_type(4)));
typedef float f32x4 __attribute__((ext_vector_type(4)));
typedef __bf16 bf16x8 __attribute__((ext_vector_type(8)));
typedef __bf16 bf16x4 __attribute__((ext_vector_type(4)));
typedef uint32_t u32x4 __attribute__((ext_vector_type(4)));

#define VMCNT(n)  asm volatile("s_waitcnt vmcnt(" #n ")" ::: "memory")
#define LGKMCNT0  asm volatile("s_waitcnt lgkmcnt(0)" ::: "memory")
#define SCHEDB    __builtin_amdgcn_sched_barrier(0)
#define SBAR      __builtin_amdgcn_s_barrier()

__device__ __forceinline__ void gload16(void* lds, const void* g)
{
    __builtin_amdgcn_global_load_lds(
        (const __attribute__((address_space(1))) uint32_t*)g,
        (__attribute__((address_space(3))) uint32_t*)lds, 16, 0, 0);
}

// ---------------------------------------------------------------------------
// K0: weight transposition to j = k*16+c layout (bf16).
// ---------------------------------------------------------------------------
__global__ __launch_bounds__(256) void prep_kernel(
    const float* __restrict__ w_off, const float* __restrict__ w_def,
    __bf16* __restrict__ woff_b, __bf16* __restrict__ wdef_b)
{
    int idx = blockIdx.x * 256 + threadIdx.x;
    if (idx < TWOK * CK) {
        int o = idx / CK, rem = idx % CK;
        int k = rem >> 4, c = rem & 15;
        woff_b[idx] = (__bf16)w_off[o * CK + c * KW + k];
    }
    if (idx < DOUT * CK) {
        int d = idx / CK, rem = idx % CK;
        int k = rem >> 4, c = rem & 15;
        wdef_b[idx] = (__bf16)w_def[d * CK + c * KW + k];
    }
}

#define BM 96
#define BN 512
#define BK 64

// ---------------------------------------------------------------------------
// R6/R7 SPLIT.  Three fused schedules (R0 full-drain, R3 counted-vmcnt, R5
// coalesced gather) all measured 78-81 us with MfmaUtil~10 / VALUBusy~10 /
// HBM~28% -- the cost is structural (8 barrier-coupled waves, 2 blocks/CU,
// no TLP to absorb gather+DMA latency).  Split: K1 = barrier-free gather ->
// A_ws bf16 [MROWS][CK] (j=k*16+c layout); K2 = pure DMA-fed GEMM.  Each
// runs at its natural throughput, and rocprof attributes time per kernel.
// ---------------------------------------------------------------------------

// K1: offsets (MFMA prologue, 6 waves x 16 windows) + gather + pack + store.
// 384 threads, 96 windows/block.  No barriers in the gather loop.
__global__ __launch_bounds__(384) void k1_gather(
    const float* __restrict__ x, const __bf16* __restrict__ woff_b,
    const float* __restrict__ b_off, __bf16* __restrict__ A_ws, int mbase)
{
    __shared__ char smem[37632];
    __bf16* WoffS = (__bf16*)smem;            // [48][392] = 37632 B
    float*  offS  = (float*)smem;             // [96][49] = 18816 B, aliased
                                              // over WoffS after a barrier

    const int t = threadIdx.x;
    const int mrel0 = blockIdx.x * BM;
    const int m0 = mbase + mrel0;
    const int wave = t >> 6, lane = t & 63;
    const int quad = lane >> 4, l16 = lane & 15;

    const int mloc = t >> 2, k4 = t & 3;
    const int Mrow = m0 + mloc;
    const int mrel = mrel0 + mloc;
    const int b    = m0 / LOUT;               // blocks never straddle batches
    const int lb   = Mrow - b * LOUT;
    const float* xb = x + (size_t)b * LLEN * CCH;

    // stage woff: 2304 16B chunks / 384 thr = 6 each
#pragma unroll
    for (int i = 0; i < 6; ++i) {
        int q = t + 384 * i;
        int row = q / 48, cc = q - row * 48;
        *(u32x4*)&WoffS[row * 392 + cc * 8] =
            *(const u32x4*)&woff_b[row * CK + cc * 8];
    }
    __syncthreads();

    // offsets MFMA: all 6 waves, 16 windows each (A-frags direct from x)
    const float* xr = x + (size_t)(m0 + wave * 16 + l16) * CK;
    f32x4 oacc[3] = {};
#pragma unroll
    for (int ks = 0; ks < 12; ++ks) {
        int k0 = ks * 32 + quad * 8;
        fx4 a0 = *(const fx4*)&xr[k0];
        fx4 a1 = *(const fx4*)&xr[k0 + 4];
        bf16x8 af;
        af[0] = (__bf16)a0.x; af[1] = (__bf16)a0.y;
        af[2] = (__bf16)a0.z; af[3] = (__bf16)a0.w;
        af[4] = (__bf16)a1.x; af[5] = (__bf16)a1.y;
        af[6] = (__bf16)a1.z; af[7] = (__bf16)a1.w;
#pragma unroll
        for (int j = 0; j < 3; ++j) {
            bf16x8 bf = *(const bf16x8*)&WoffS[(j * 16 + l16) * 392 + k0];
            oacc[j] = __builtin_amdgcn_mfma_f32_16x16x32_bf16(af, bf, oacc[j], 0, 0, 0);
        }
    }
    float bo[3];
#pragma unroll
    for (int j = 0; j < 3; ++j) bo[j] = b_off[j * 16 + l16];
    __syncthreads();                          // all WoffS reads complete
#pragma unroll
    for (int j = 0; j < 3; ++j)
#pragma unroll
        for (int r = 0; r < 4; ++r)
            offS[(wave * 16 + quad * 4 + r) * 49 + j * 16 + l16] = oacc[j][r] + bo[j];
    __syncthreads();

    // pack this thread's 6 (dy,dx) pairs
    float dyv[6], dxv[6];
#pragma unroll
    for (int cc = 0; cc < 6; ++cc) {
        int kk = 4 * cc + k4;
        dyv[cc] = offS[mloc * 49 + 2 * kk];
        dxv[cc] = offS[mloc * 49 + 2 * kk + 1];
    }

    // gather + pack + store: barrier-free, iterations independent
    for (int cc = 0; cc < 6; ++cc) {
        int kk = 4 * cc + k4;
        float dy = dyv[cc], dx = dxv[cc];
        float wy  = fmaxf(0.f, 1.f - fabsf(dy));
        float px  = (float)(lb * KW + kk) + dx;
        float x0f = floorf(px);
        float lw  = px - x0f;
        int   i0  = (int)x0f;
        bool valid = (px > -1.0f) && (px < (float)LLEN);
        float w0 = (valid && i0 >= 0)         ? (1.f - lw) * wy : 0.f;
        float w1 = (valid && (i0 + 1) < LLEN) ? lw * wy         : 0.f;
        int i0c = min(max(i0, 0), LLEN - 1);
        int i1c = min(max(i0 + 1, 0), LLEN - 1);
        const fx4* p0 = (const fx4*)&xb[(size_t)i0c * CCH];
        const fx4* p1 = (const fx4*)&xb[(size_t)i1c * CCH];
        fx4 g0[4], g1[4];
#pragma unroll
        for (int q = 0; q < 4; ++q) { g0[q] = p0[q]; g1[q] = p1[q]; }
        bf16x8 oa, ob;
#pragma unroll
        for (int q = 0; q < 2; ++q) {
            fx4 v0 = g0[q], v1 = g1[q];
            oa[q * 4 + 0] = (__bf16)(w0 * v0.x + w1 * v1.x);
            oa[q * 4 + 1] = (__bf16)(w0 * v0.y + w1 * v1.y);
            oa[q * 4 + 2] = (__bf16)(w0 * v0.z + w1 * v1.z);
            oa[q * 4 + 3] = (__bf16)(w0 * v0.w + w1 * v1.w);
        }
#pragma unroll
        for (int q = 0; q < 2; ++q) {
            fx4 v0 = g0[q + 2], v1 = g1[q + 2];
            ob[q * 4 + 0] = (__bf16)(w0 * v0.x + w1 * v1.x);
            ob[q * 4 + 1] = (__bf16)(w0 * v0.y + w1 * v1.y);
            ob[q * 4 + 2] = (__bf16)(w0 * v0.z + w1 * v1.z);
            ob[q * 4 + 3] = (__bf16)(w0 * v0.w + w1 * v1.w);
        }
        // A_ws row mrel, elements kk*16..kk*16+15: 32 B/thread, k4-lanes
        // consecutive -> 128 B contiguous per window per wave-instr.
        __bf16* dst = A_ws + (size_t)mrel * CK + kk * 16;
        *(bf16x8*)dst       = oa;
        *(bf16x8*)(dst + 8) = ob;
    }
}

// K2: dense GEMM [rows x 384] x [384 x 512], A+B DMA'd per 32-wide phase,
// double-buffered, counted vmcnt, 2 barriers/phase.  512 thr, 8 waves
// (2x4, wave tile 48x128), 96 rows/block.  LDS 76 KB -> 2 blocks/CU.
__global__ __launch_bounds__(512) void k2_gemm(
    const __bf16* __restrict__ A_ws, const __bf16* __restrict__ Bw,
    const float* __restrict__ bias, float* __restrict__ out, int mbase)
{
    __shared__ char smem[77824];
    __bf16* As0 = (__bf16*)smem;              // [96][32] = 6144 B
    __bf16* As1 = (__bf16*)(smem + 6144);
    __bf16* Bs0 = (__bf16*)(smem + 12288);    // [512][32] = 32768 B
    __bf16* Bs1 = (__bf16*)(smem + 45056);

    const int t = threadIdx.x;
    const int mrel0 = blockIdx.x * BM;
    const int wave = t >> 6, lane = t & 63;
    const int quad = lane >> 4, l16 = lane & 15;
    const int wr = wave >> 2, wc = wave & 3;

    // DMA one 32-wide phase: Bs 2048 chunks (4/thr) + As 384 chunks (t<384).
    // LDS dest linear in chunk index (wave-uniform base + lane*16); source
    // carries the XOR swizzle so the ds_read pattern below is conflict-mild.
    auto dma = [&](int p, __bf16* AsB, __bf16* BsB) {
#pragma unroll
        for (int it = 0; it < 4; ++it) {
            int q = it * 512 + t;
            int c = q >> 2, s = q & 3;
            int ss = s ^ ((c >> 1) & 3);
            gload16(&BsB[q * 8], Bw + (size_t)c * CK + p * 32 + ss * 8);
        }
        if (t < 384) {
            int row = t >> 2, g = t & 3;
            int gg = g ^ ((row >> 1) & 3);
            gload16(&AsB[t * 8],
                    A_ws + (size_t)(mrel0 + row) * CK + p * 32 + gg * 8);
        }
    };

    f32x4 acc[3][8] = {};

    auto mfma_phase = [&](const __bf16* AsB, const __bf16* BsB) {
        bf16x8 af[3], bfr[8];
#pragma unroll
        for (int i = 0; i < 3; ++i) {
            int row = wr * 48 + i * 16 + l16;
            af[i] = *(const bf16x8*)&AsB[row * 32 + ((quad ^ ((row >> 1) & 3)) * 8)];
        }
#pragma unroll
        for (int j = 0; j < 8; ++j) {
            int col = wc * 128 + j * 16 + l16;
            bfr[j] = *(const bf16x8*)&BsB[col * 32 + ((quad ^ ((col >> 1) & 3)) * 8)];
        }
#pragma unroll
        for (int i = 0; i < 3; ++i)
#pragma unroll
            for (int j = 0; j < 8; ++j)
                acc[i][j] = __builtin_amdgcn_mfma_f32_16x16x32_bf16(
                    af[i], bfr[j], acc[i][j], 0, 0, 0);
    };

    dma(0, As0, Bs0);                         // D(0)
#pragma unroll
    for (int p = 0; p < 12; ++p) {
        __bf16* Ac = (p & 1) ? As1 : As0;
        __bf16* Bc = (p & 1) ? Bs1 : Bs0;
        __bf16* An = (p & 1) ? As0 : As1;
        __bf16* Bn = (p & 1) ? Bs0 : Bs1;
        if (p < 11) dma(p + 1, An, Bn);       // D(p+1) flies across barriers
        SCHEDB;
        // wait own D(p); D(p+1) stays in flight (waves 0-5: 5 loads/phase,
        // waves 6-7: 4)
        if (p < 11) { if (wave < 6) { VMCNT(5); } else { VMCNT(4); } }
        else        { VMCNT(0); }
        SCHEDB;
        SBAR;                                 // buf cur filled by all waves
        SCHEDB;
        __builtin_amdgcn_s_setprio(1);
        mfma_phase(Ac, Bc);
        __builtin_amdgcn_s_setprio(0);
        SCHEDB;
        SBAR;                                 // cur consumed; D(p+2) may
        SCHEDB;                               // overwrite it next iter
    }

    // epilogue: D[row=quad*4+r][col=l16]
#pragma unroll
    for (int j = 0; j < 8; ++j) {
        int col = wc * 128 + j * 16 + l16;
        float bj = bias[col];
#pragma unroll
        for (int i = 0; i < 3; ++i) {
            int rowb = mbase + mrel0 + wr * 48 + i * 16 + quad * 4;
#pragma unroll
            for (int r = 0; r < 4; ++r)
                out[(size_t)(rowb + r) * DOUT + col] = acc[i][j][r] + bj;
        }
    }
}

// ---------------------------------------------------------------------------
// Fallback: R5 fused kernel (used only if d_ws is too small for A_ws).
// ---------------------------------------------------------------------------
__global__ __launch_bounds__(512) void gemm_fused(
    const float* __restrict__ x, const __bf16* __restrict__ woff_b,
    const float* __restrict__ b_off, const __bf16* __restrict__ Bw,
    const float* __restrict__ bias, float* __restrict__ out)
{
    __shared__ char smem[77824];
    __bf16* As  = (__bf16*)smem;
    __bf16* Bs0 = (__bf16*)(smem + 12288);
    __bf16* Bs1 = (__bf16*)(smem + 45056);
    __bf16* WoffS = (__bf16*)smem;
    float*  offS  = (float*)(smem + 45056);

    const int t = threadIdx.x;
    const int m0 = blockIdx.x * BM;
    const int wave = t >> 6, lane = t & 63;
    const int quad = lane >> 4, l16 = lane & 15;
    const int wr = wave >> 2, wc = wave & 3;

    const int mloc = t >> 2, k4 = t & 3;
    const int Mrow = m0 + mloc;
    const int b    = m0 / LOUT;
    const int lb   = Mrow - b * LOUT;
    const float* xb = x + (size_t)b * LLEN * CCH;

#pragma unroll
    for (int i = 0; i < 5; ++i) {
        int q = t + 512 * i;
        if (q < 2304) {
            int row = q / 48, cc = q - row * 48;
            *(u32x4*)&WoffS[row * 392 + cc * 8] =
                *(const u32x4*)&woff_b[row * CK + cc * 8];
        }
    }
    __syncthreads();

    if (wave < 6) {
        const float* xr = x + (size_t)(m0 + wave * 16 + l16) * CK;
        f32x4 oacc[3] = {};
#pragma unroll
        for (int ks = 0; ks < 12; ++ks) {
            int k0 = ks * 32 + quad * 8;
            fx4 a0 = *(const fx4*)&xr[k0];
            fx4 a1 = *(const fx4*)&xr[k0 + 4];
            bf16x8 af;
            af[0] = (__bf16)a0.x; af[1] = (__bf16)a0.y;
            af[2] = (__bf16)a0.z; af[3] = (__bf16)a0.w;
            af[4] = (__bf16)a1.x; af[5] = (__bf16)a1.y;
            af[6] = (__bf16)a1.z; af[7] = (__bf16)a1.w;
#pragma unroll
            for (int j = 0; j < 3; ++j) {
                bf16x8 bf = *(const bf16x8*)&WoffS[(j * 16 + l16) * 392 + k0];
                oacc[j] = __builtin_amdgcn_mfma_f32_16x16x32_bf16(af, bf, oacc[j], 0, 0, 0);
            }
        }
        float bo[3];
#pragma unroll
        for (int j = 0; j < 3; ++j) bo[j] = b_off[j * 16 + l16];
#pragma unroll
        for (int j = 0; j < 3; ++j)
#pragma unroll
            for (int r = 0; r < 4; ++r)
                offS[(wave * 16 + quad * 4 + r) * 49 + j * 16 + l16] = oacc[j][r] + bo[j];
    }
    __syncthreads();

    uint32_t dxyr[6];
    if (t < 4 * BM) {
#pragma unroll
        for (int cc = 0; cc < 6; ++cc) {
            int kk = 4 * cc + k4;
            float dy = offS[mloc * 49 + 2 * kk];
            float dx = offS[mloc * 49 + 2 * kk + 1];
            union { __bf16 h[2]; uint32_t u; } p;
            p.h[0] = (__bf16)dy; p.h[1] = (__bf16)dx;
            dxyr[cc] = p.u;
        }
    }

    f32x4 acc[3][8] = {};
    fx4 g0[4], g1[4];
    float w0, w1;

    auto load_pair = [&](uint32_t pk, int kk) {
        union { uint32_t u; __bf16 h[2]; } p; p.u = pk;
        float dy = (float)p.h[0], dx = (float)p.h[1];
        float wy  = fmaxf(0.f, 1.f - fabsf(dy));
        float px  = (float)(lb * KW + kk) + dx;
        float x0f = floorf(px);
        float lw  = px - x0f;
        int   i0  = (int)x0f;
        bool valid = (px > -1.0f) && (px < (float)LLEN);
        w0 = (valid && i0 >= 0)         ? (1.f - lw) * wy : 0.f;
        w1 = (valid && (i0 + 1) < LLEN) ? lw * wy         : 0.f;
        int i0c = min(max(i0, 0), LLEN - 1);
        int i1c = min(max(i0 + 1, 0), LLEN - 1);
        const fx4* p0 = (const fx4*)&xb[(size_t)i0c * CCH];
        const fx4* p1 = (const fx4*)&xb[(size_t)i1c * CCH];
#pragma unroll
        for (int q = 0; q < 4; ++q) { g0[q] = p0[q]; g1[q] = p1[q]; }
    };

    auto dma_phase = [&](int ph, __bf16* buf) {
#pragma unroll
        for (int it = 0; it < 4; ++it) {
            int q = it * 512 + t;
            int c = q >> 2, s = q & 3;
            int ss = s ^ ((c >> 1) & 3);
            gload16(&buf[q * 8], Bw + (size_t)c * CK + ph * 32 + ss * 8);
        }
    };

    auto mfma_phase = [&](int ks, const __bf16* Bsb) {
        bf16x8 af[3], bfr[8];
#pragma unroll
        for (int i = 0; i < 3; ++i) {
            int row = wr * 48 + i * 16 + l16;
            af[i] = *(const bf16x8*)&As[row * BK + (((ks * 4 + quad) ^ (row & 7)) * 8)];
        }
#pragma unroll
        for (int j = 0; j < 8; ++j) {
            int col = wc * 128 + j * 16 + l16;
            bfr[j] = *(const bf16x8*)&Bsb[col * 32 + ((quad ^ ((col >> 1) & 3)) * 8)];
        }
#pragma unroll
        for (int i = 0; i < 3; ++i)
#pragma unroll
            for (int j = 0; j < 8; ++j)
                acc[i][j] = __builtin_amdgcn_mfma_f32_16x16x32_bf16(
                    af[i], bfr[j], acc[i][j], 0, 0, 0);
    };

    if (t < 4 * BM) load_pair(dxyr[0], k4);
    SCHEDB;
    dma_phase(0, Bs0);
    SCHEDB;

#pragma unroll
    for (int cc = 0; cc < 6; ++cc) {
        SBAR;
        SCHEDB;
        VMCNT(4);
        SCHEDB;
        if (t < 4 * BM) {
            bf16x8 oa, ob;
#pragma unroll
            for (int q = 0; q < 2; ++q) {
                fx4 v0 = g0[q], v1 = g1[q];
                oa[q * 4 + 0] = (__bf16)(w0 * v0.x + w1 * v1.x);
                oa[q * 4 + 1] = (__bf16)(w0 * v0.y + w1 * v1.y);
                oa[q * 4 + 2] = (__bf16)(w0 * v0.z + w1 * v1.z);
                oa[q * 4 + 3] = (__bf16)(w0 * v0.w + w1 * v1.w);
            }
#pragma unroll
            for (int q = 0; q < 2; ++q) {
                fx4 v0 = g0[q + 2], v1 = g1[q + 2];
                ob[q * 4 + 0] = (__bf16)(w0 * v0.x + w1 * v1.x);
                ob[q * 4 + 1] = (__bf16)(w0 * v0.y + w1 * v1.y);
                ob[q * 4 + 2] = (__bf16)(w0 * v0.z + w1 * v1.z);
                ob[q * 4 + 3] = (__bf16)(w0 * v0.w + w1 * v1.w);
            }
            int g = 2 * k4;
            *(bf16x8*)&As[mloc * BK + ((g ^ (mloc & 7)) * 8)]       = oa;
            *(bf16x8*)&As[mloc * BK + (((g + 1) ^ (mloc & 7)) * 8)] = ob;
        }
        SCHEDB;
        dma_phase(2 * cc + 1, Bs1);
        SCHEDB;
        if (cc + 1 < 6 && t < 4 * BM)
            load_pair(dxyr[cc + 1], 4 * (cc + 1) + k4);
        SCHEDB;
        LGKMCNT0;
        SCHEDB;
        SBAR;
        SCHEDB;
        if (cc < 5) { if (wave < 6) { VMCNT(12); } else { VMCNT(4); } }
        else        { VMCNT(4); }
        SCHEDB;
        SBAR;
        SCHEDB;
        __builtin_amdgcn_s_setprio(1);
        mfma_phase(0, Bs0);
        __builtin_amdgcn_s_setprio(0);
        SCHEDB;
        if (cc < 5) { if (wave < 6) { VMCNT(8); } else { VMCNT(0); } }
        else        { VMCNT(0); }
        SCHEDB;
        SBAR;
        SCHEDB;
        if (cc < 5) dma_phase(2 * cc + 2, Bs0);
        SCHEDB;
        __builtin_amdgcn_s_setprio(1);
        mfma_phase(1, Bs1);
        __builtin_amdgcn_s_setprio(0);
        SCHEDB;
    }

#pragma unroll
    for (int j = 0; j < 8; ++j) {
        int col = wc * 128 + j * 16 + l16;
        float bj = bias[col];
#pragma unroll
        for (int i = 0; i < 3; ++i) {
            int rowb = m0 + wr * 48 + i * 16 + quad * 4;
#pragma unroll
            for (int r = 0; r < 4; ++r)
                out[(size_t)(rowb + r) * DOUT + col] = acc[i][j][r] + bj;
        }
    }
}

// ---------------------------------------------------------------------------
extern "C" void kernel_launch(void* const* d_in, const int* in_sizes, int n_in,
                              void* d_out, int out_size, void* d_ws, size_t ws_size,
                              hipStream_t stream)
{
    const float* x     = (const float*)d_in[0];
    const float* w_off = (const float*)d_in[1];
    const float* b_off = (const float*)d_in[2];
    const float* w_def = (const float*)d_in[3];
    const float* b_def = (const float*)d_in[4];
    float* out = (float*)d_out;

    char* ws = (char*)d_ws;
    __bf16* wdef_b = (__bf16*)ws;                 // 393,216 B
    __bf16* woff_b = (__bf16*)(ws + 393216);      //  36,864 B
    __bf16* A_ws   = (__bf16*)(ws + 430080);      // up to 37,748,736 B

    prep_kernel<<<768, 256, 0, stream>>>(w_off, w_def, woff_b, wdef_b);

    const size_t afull = (size_t)MROWS * CK * 2;  // 37.75 MB
    int S = -1;
    for (int s = 1; s <= 32; s <<= 1) {
        if (430080 + afull / s <= ws_size) { S = s; break; }
    }
    if (S > 0) {
        int rows = MROWS / S;                     // multiple of 96 (and LOUT)
        int nb   = rows / BM;
        for (int c = 0; c < S; ++c) {
            int mb = c * rows;
            k1_gather<<<nb, 384, 0, stream>>>(x, woff_b, b_off, A_ws, mb);
            k2_gemm<<<nb, 512, 0, stream>>>(A_ws, wdef_b, b_def, out, mb);
        }
    } else {
        gemm_fused<<<MROWS / BM, 512, 0, stream>>>(x, woff_b, b_off, wdef_b, b_def, out);
    }
}

// Round 8
// 215.706 us; speedup vs baseline: 1.0028x; 1.0028x over previous
//
#include <hip/hip_runtime.h>
#include <stdint.h>

// Problem constants
#define BATCH 32
#define LLEN  36864
#define CCH   16
#define DOUT  512
#define KW    24
#define LOUT  1536            // LLEN / KW
#define MROWS (BATCH * LOUT)  // 49152 windows
#define CK    384             // CCH * KW (inner dot length)
#define TWOK  48

typedef float fx4 __attribute__((ext_vector_type(4)));
typedef float f32x4 __attribute__((ext_vector_type(4)));
typedef __bf16 bf16x8 __attribute__((ext_vector_type(8)));
typedef __bf16 bf16x4 __attribute__((ext_vector_type(4)));
typedef uint32_t u32x4 __attribute__((ext_vector_type(4)));

#define VMCNT(n)  asm volatile("s_waitcnt vmcnt(" #n ")" ::: "memory")
#define LGKMCNT0  asm volatile("s_waitcnt lgkmcnt(0)" ::: "memory")
#define SCHEDB    __builtin_amdgcn_sched_barrier(0)
#define SBAR      __builtin_amdgcn_s_barrier()

__device__ __forceinline__ void gload16(void* lds, const void* g)
{
    __builtin_amdgcn_global_load_lds(
        (const __attribute__((address_space(1))) uint32_t*)g,
        (__attribute__((address_space(3))) uint32_t*)lds, 16, 0, 0);
}

// ---------------------------------------------------------------------------
// K0: weight transposition to j = k*16+c layout (bf16).
// ---------------------------------------------------------------------------
__global__ __launch_bounds__(256) void prep_kernel(
    const float* __restrict__ w_off, const float* __restrict__ w_def,
    __bf16* __restrict__ woff_b, __bf16* __restrict__ wdef_b)
{
    int idx = blockIdx.x * 256 + threadIdx.x;
    if (idx < TWOK * CK) {
        int o = idx / CK, rem = idx % CK;
        int k = rem >> 4, c = rem & 15;
        woff_b[idx] = (__bf16)w_off[o * CK + c * KW + k];
    }
    if (idx < DOUT * CK) {
        int d = idx / CK, rem = idx % CK;
        int k = rem >> 4, c = rem & 15;
        wdef_b[idx] = (__bf16)w_def[d * CK + c * KW + k];
    }
}

#define BM 96
#define BN 512
#define BK 64

// ---------------------------------------------------------------------------
// R8: split retained; k1 UNCHANGED (control); k2 REBUILT for TLP.
// R7 showed k1+k2 ~= 98 us total, both < 65 us (hidden below the harness's
// 65 us ws-fill in top-5).  Old k2 = same 8-wave 2-blocks/CU counted-vmcnt
// convoy as the 78-us fused loop.  New k2: 64x128 tiles, 256 thr / 4 waves,
// LDS 24 KB (dbuf BK=32), grid 3072 -> 5-6 independent blocks/CU.
// Delta(bench) == Delta(k2): clean attribution.
// ---------------------------------------------------------------------------

// K1: offsets (MFMA prologue, 6 waves x 16 windows) + gather + pack + store.
// 384 threads, 96 windows/block.  No barriers in the gather loop.
__global__ __launch_bounds__(384) void k1_gather(
    const float* __restrict__ x, const __bf16* __restrict__ woff_b,
    const float* __restrict__ b_off, __bf16* __restrict__ A_ws, int mbase)
{
    __shared__ char smem[37632];
    __bf16* WoffS = (__bf16*)smem;            // [48][392] = 37632 B
    float*  offS  = (float*)smem;             // [96][49] = 18816 B, aliased
                                              // over WoffS after a barrier

    const int t = threadIdx.x;
    const int mrel0 = blockIdx.x * BM;
    const int m0 = mbase + mrel0;
    const int wave = t >> 6, lane = t & 63;
    const int quad = lane >> 4, l16 = lane & 15;

    const int mloc = t >> 2, k4 = t & 3;
    const int Mrow = m0 + mloc;
    const int mrel = mrel0 + mloc;
    const int b    = m0 / LOUT;               // blocks never straddle batches
    const int lb   = Mrow - b * LOUT;
    const float* xb = x + (size_t)b * LLEN * CCH;

    // stage woff: 2304 16B chunks / 384 thr = 6 each
#pragma unroll
    for (int i = 0; i < 6; ++i) {
        int q = t + 384 * i;
        int row = q / 48, cc = q - row * 48;
        *(u32x4*)&WoffS[row * 392 + cc * 8] =
            *(const u32x4*)&woff_b[row * CK + cc * 8];
    }
    __syncthreads();

    // offsets MFMA: all 6 waves, 16 windows each (A-frags direct from x)
    const float* xr = x + (size_t)(m0 + wave * 16 + l16) * CK;
    f32x4 oacc[3] = {};
#pragma unroll
    for (int ks = 0; ks < 12; ++ks) {
        int k0 = ks * 32 + quad * 8;
        fx4 a0 = *(const fx4*)&xr[k0];
        fx4 a1 = *(const fx4*)&xr[k0 + 4];
        bf16x8 af;
        af[0] = (__bf16)a0.x; af[1] = (__bf16)a0.y;
        af[2] = (__bf16)a0.z; af[3] = (__bf16)a0.w;
        af[4] = (__bf16)a1.x; af[5] = (__bf16)a1.y;
        af[6] = (__bf16)a1.z; af[7] = (__bf16)a1.w;
#pragma unroll
        for (int j = 0; j < 3; ++j) {
            bf16x8 bf = *(const bf16x8*)&WoffS[(j * 16 + l16) * 392 + k0];
            oacc[j] = __builtin_amdgcn_mfma_f32_16x16x32_bf16(af, bf, oacc[j], 0, 0, 0);
        }
    }
    float bo[3];
#pragma unroll
    for (int j = 0; j < 3; ++j) bo[j] = b_off[j * 16 + l16];
    __syncthreads();                          // all WoffS reads complete
#pragma unroll
    for (int j = 0; j < 3; ++j)
#pragma unroll
        for (int r = 0; r < 4; ++r)
            offS[(wave * 16 + quad * 4 + r) * 49 + j * 16 + l16] = oacc[j][r] + bo[j];
    __syncthreads();

    // pack this thread's 6 (dy,dx) pairs
    float dyv[6], dxv[6];
#pragma unroll
    for (int cc = 0; cc < 6; ++cc) {
        int kk = 4 * cc + k4;
        dyv[cc] = offS[mloc * 49 + 2 * kk];
        dxv[cc] = offS[mloc * 49 + 2 * kk + 1];
    }

    // gather + pack + store: barrier-free, iterations independent
    for (int cc = 0; cc < 6; ++cc) {
        int kk = 4 * cc + k4;
        float dy = dyv[cc], dx = dxv[cc];
        float wy  = fmaxf(0.f, 1.f - fabsf(dy));
        float px  = (float)(lb * KW + kk) + dx;
        float x0f = floorf(px);
        float lw  = px - x0f;
        int   i0  = (int)x0f;
        bool valid = (px > -1.0f) && (px < (float)LLEN);
        float w0 = (valid && i0 >= 0)         ? (1.f - lw) * wy : 0.f;
        float w1 = (valid && (i0 + 1) < LLEN) ? lw * wy         : 0.f;
        int i0c = min(max(i0, 0), LLEN - 1);
        int i1c = min(max(i0 + 1, 0), LLEN - 1);
        const fx4* p0 = (const fx4*)&xb[(size_t)i0c * CCH];
        const fx4* p1 = (const fx4*)&xb[(size_t)i1c * CCH];
        fx4 g0[4], g1[4];
#pragma unroll
        for (int q = 0; q < 4; ++q) { g0[q] = p0[q]; g1[q] = p1[q]; }
        bf16x8 oa, ob;
#pragma unroll
        for (int q = 0; q < 2; ++q) {
            fx4 v0 = g0[q], v1 = g1[q];
            oa[q * 4 + 0] = (__bf16)(w0 * v0.x + w1 * v1.x);
            oa[q * 4 + 1] = (__bf16)(w0 * v0.y + w1 * v1.y);
            oa[q * 4 + 2] = (__bf16)(w0 * v0.z + w1 * v1.z);
            oa[q * 4 + 3] = (__bf16)(w0 * v0.w + w1 * v1.w);
        }
#pragma unroll
        for (int q = 0; q < 2; ++q) {
            fx4 v0 = g0[q + 2], v1 = g1[q + 2];
            ob[q * 4 + 0] = (__bf16)(w0 * v0.x + w1 * v1.x);
            ob[q * 4 + 1] = (__bf16)(w0 * v0.y + w1 * v1.y);
            ob[q * 4 + 2] = (__bf16)(w0 * v0.z + w1 * v1.z);
            ob[q * 4 + 3] = (__bf16)(w0 * v0.w + w1 * v1.w);
        }
        // A_ws row mrel, elements kk*16..kk*16+15: 32 B/thread, k4-lanes
        // consecutive -> 128 B contiguous per window per wave-instr.
        __bf16* dst = A_ws + (size_t)mrel * CK + kk * 16;
        *(bf16x8*)dst       = oa;
        *(bf16x8*)(dst + 8) = ob;
    }
}

// ---------------------------------------------------------------------------
// K2 (rebuilt): dense GEMM [rows x 384] x [384 x 512]^T-ish (both operands
// row-major in the j=k*16+c layout).  Tile 64x128, 256 thr = 4 waves (2x2,
// wave tile 32x64), BK=32 double-buffered, counted vmcnt(3), 2 barriers per
// phase.  LDS = 2*(4 KB A + 8 KB B) = 24 KB -> 5-6 blocks/CU; blocks fully
// independent.  Grid = (rows/64)*4.
// ---------------------------------------------------------------------------
__global__ __launch_bounds__(256, 4) void k2_gemm(
    const __bf16* __restrict__ A_ws, const __bf16* __restrict__ Bw,
    const float* __restrict__ bias, float* __restrict__ out, int mbase)
{
    __shared__ char smem[24576];
    __bf16* As0 = (__bf16*)smem;              // [64][32]  = 4096 B
    __bf16* Bs0 = (__bf16*)(smem + 4096);     // [128][32] = 8192 B
    __bf16* As1 = (__bf16*)(smem + 12288);
    __bf16* Bs1 = (__bf16*)(smem + 16384);

    const int t = threadIdx.x;
    const int mtile = blockIdx.x >> 2;
    const int n0 = (blockIdx.x & 3) * 128;
    const int m0rel = mtile * 64;
    const int wave = t >> 6, lane = t & 63;
    const int quad = lane >> 4, l16 = lane & 15;
    const int wr = wave >> 1, wc = wave & 1;  // 2x2 waves: wave tile 32x64

    // DMA one 32-wide phase: B 512 chunks + A 256 chunks = 768 / 256 thr = 3.
    // LDS dest linear in chunk index; source pre-swizzled so the ds_read
    // pattern below is conflict-mild (same scheme as proven R6 k2).
    auto dma = [&](int p, __bf16* AsB, __bf16* BsB) {
#pragma unroll
        for (int it = 0; it < 3; ++it) {
            int q = it * 256 + t;
            if (q < 512) {                    // B chunk
                int c = q >> 2, s = q & 3;
                int ss = s ^ ((c >> 1) & 3);
                gload16(&BsB[q * 8], Bw + (size_t)(n0 + c) * CK + p * 32 + ss * 8);
            } else {                          // A chunk
                int q2 = q - 512;
                int row = q2 >> 2, s = q2 & 3;
                int ss = s ^ ((row >> 1) & 3);
                gload16(&AsB[q2 * 8],
                        A_ws + (size_t)(m0rel + row) * CK + p * 32 + ss * 8);
            }
        }
    };

    f32x4 acc[2][4] = {};

    auto mfma_phase = [&](const __bf16* AsB, const __bf16* BsB) {
        bf16x8 af[2], bfr[4];
#pragma unroll
        for (int i = 0; i < 2; ++i) {
            int row = wr * 32 + i * 16 + l16;
            af[i] = *(const bf16x8*)&AsB[row * 32 + ((quad ^ ((row >> 1) & 3)) * 8)];
        }
#pragma unroll
        for (int j = 0; j < 4; ++j) {
            int col = wc * 64 + j * 16 + l16;
            bfr[j] = *(const bf16x8*)&BsB[col * 32 + ((quad ^ ((col >> 1) & 3)) * 8)];
        }
#pragma unroll
        for (int i = 0; i < 2; ++i)
#pragma unroll
            for (int j = 0; j < 4; ++j)
                acc[i][j] = __builtin_amdgcn_mfma_f32_16x16x32_bf16(
                    af[i], bfr[j], acc[i][j], 0, 0, 0);
    };

    dma(0, As0, Bs0);                         // D(0)
#pragma unroll
    for (int p = 0; p < 12; ++p) {
        __bf16* Ac = (p & 1) ? As1 : As0;
        __bf16* Bc = (p & 1) ? Bs1 : Bs0;
        __bf16* An = (p & 1) ? As0 : As1;
        __bf16* Bn = (p & 1) ? Bs0 : Bs1;
        if (p < 11) dma(p + 1, An, Bn);       // D(p+1) flies across barrier
        SCHEDB;
        if (p < 11) { VMCNT(3); }             // own D(p) done, D(p+1) in flight
        else        { VMCNT(0); }
        SCHEDB;
        SBAR;                                 // cur buffers filled by all waves
        SCHEDB;
        __builtin_amdgcn_s_setprio(1);
        mfma_phase(Ac, Bc);
        __builtin_amdgcn_s_setprio(0);
        SCHEDB;
        if (p < 11) { SBAR; SCHEDB; }         // cur consumed; D(p+2) may
                                              // overwrite it next iter
    }

    // epilogue: D[row=quad*4+r][col=l16]
#pragma unroll
    for (int j = 0; j < 4; ++j) {
        int col = n0 + wc * 64 + j * 16 + l16;
        float bj = bias[col];
#pragma unroll
        for (int i = 0; i < 2; ++i) {
            int rowb = mbase + m0rel + wr * 32 + i * 16 + quad * 4;
#pragma unroll
            for (int r = 0; r < 4; ++r)
                out[(size_t)(rowb + r) * DOUT + col] = acc[i][j][r] + bj;
        }
    }
}

// ---------------------------------------------------------------------------
// Fallback: R5 fused kernel (used only if d_ws is too small for A_ws).
// ---------------------------------------------------------------------------
__global__ __launch_bounds__(512) void gemm_fused(
    const float* __restrict__ x, const __bf16* __restrict__ woff_b,
    const float* __restrict__ b_off, const __bf16* __restrict__ Bw,
    const float* __restrict__ bias, float* __restrict__ out)
{
    __shared__ char smem[77824];
    __bf16* As  = (__bf16*)smem;
    __bf16* Bs0 = (__bf16*)(smem + 12288);
    __bf16* Bs1 = (__bf16*)(smem + 45056);
    __bf16* WoffS = (__bf16*)smem;
    float*  offS  = (float*)(smem + 45056);

    const int t = threadIdx.x;
    const int m0 = blockIdx.x * BM;
    const int wave = t >> 6, lane = t & 63;
    const int quad = lane >> 4, l16 = lane & 15;
    const int wr = wave >> 2, wc = wave & 3;

    const int mloc = t >> 2, k4 = t & 3;
    const int Mrow = m0 + mloc;
    const int b    = m0 / LOUT;
    const int lb   = Mrow - b * LOUT;
    const float* xb = x + (size_t)b * LLEN * CCH;

#pragma unroll
    for (int i = 0; i < 5; ++i) {
        int q = t + 512 * i;
        if (q < 2304) {
            int row = q / 48, cc = q - row * 48;
            *(u32x4*)&WoffS[row * 392 + cc * 8] =
                *(const u32x4*)&woff_b[row * CK + cc * 8];
        }
    }
    __syncthreads();

    if (wave < 6) {
        const float* xr = x + (size_t)(m0 + wave * 16 + l16) * CK;
        f32x4 oacc[3] = {};
#pragma unroll
        for (int ks = 0; ks < 12; ++ks) {
            int k0 = ks * 32 + quad * 8;
            fx4 a0 = *(const fx4*)&xr[k0];
            fx4 a1 = *(const fx4*)&xr[k0 + 4];
            bf16x8 af;
            af[0] = (__bf16)a0.x; af[1] = (__bf16)a0.y;
            af[2] = (__bf16)a0.z; af[3] = (__bf16)a0.w;
            af[4] = (__bf16)a1.x; af[5] = (__bf16)a1.y;
            af[6] = (__bf16)a1.z; af[7] = (__bf16)a1.w;
#pragma unroll
            for (int j = 0; j < 3; ++j) {
                bf16x8 bf = *(const bf16x8*)&WoffS[(j * 16 + l16) * 392 + k0];
                oacc[j] = __builtin_amdgcn_mfma_f32_16x16x32_bf16(af, bf, oacc[j], 0, 0, 0);
            }
        }
        float bo[3];
#pragma unroll
        for (int j = 0; j < 3; ++j) bo[j] = b_off[j * 16 + l16];
#pragma unroll
        for (int j = 0; j < 3; ++j)
#pragma unroll
            for (int r = 0; r < 4; ++r)
                offS[(wave * 16 + quad * 4 + r) * 49 + j * 16 + l16] = oacc[j][r] + bo[j];
    }
    __syncthreads();

    uint32_t dxyr[6];
    if (t < 4 * BM) {
#pragma unroll
        for (int cc = 0; cc < 6; ++cc) {
            int kk = 4 * cc + k4;
            float dy = offS[mloc * 49 + 2 * kk];
            float dx = offS[mloc * 49 + 2 * kk + 1];
            union { __bf16 h[2]; uint32_t u; } p;
            p.h[0] = (__bf16)dy; p.h[1] = (__bf16)dx;
            dxyr[cc] = p.u;
        }
    }

    f32x4 acc[3][8] = {};
    fx4 g0[4], g1[4];
    float w0, w1;

    auto load_pair = [&](uint32_t pk, int kk) {
        union { uint32_t u; __bf16 h[2]; } p; p.u = pk;
        float dy = (float)p.h[0], dx = (float)p.h[1];
        float wy  = fmaxf(0.f, 1.f - fabsf(dy));
        float px  = (float)(lb * KW + kk) + dx;
        float x0f = floorf(px);
        float lw  = px - x0f;
        int   i0  = (int)x0f;
        bool valid = (px > -1.0f) && (px < (float)LLEN);
        w0 = (valid && i0 >= 0)         ? (1.f - lw) * wy : 0.f;
        w1 = (valid && (i0 + 1) < LLEN) ? lw * wy         : 0.f;
        int i0c = min(max(i0, 0), LLEN - 1);
        int i1c = min(max(i0 + 1, 0), LLEN - 1);
        const fx4* p0 = (const fx4*)&xb[(size_t)i0c * CCH];
        const fx4* p1 = (const fx4*)&xb[(size_t)i1c * CCH];
#pragma unroll
        for (int q = 0; q < 4; ++q) { g0[q] = p0[q]; g1[q] = p1[q]; }
    };

    auto dma_phase = [&](int ph, __bf16* buf) {
#pragma unroll
        for (int it = 0; it < 4; ++it) {
            int q = it * 512 + t;
            int c = q >> 2, s = q & 3;
            int ss = s ^ ((c >> 1) & 3);
            gload16(&buf[q * 8], Bw + (size_t)c * CK + ph * 32 + ss * 8);
        }
    };

    auto mfma_phase = [&](int ks, const __bf16* Bsb) {
        bf16x8 af[3], bfr[8];
#pragma unroll
        for (int i = 0; i < 3; ++i) {
            int row = wr * 48 + i * 16 + l16;
            af[i] = *(const bf16x8*)&As[row * BK + (((ks * 4 + quad) ^ (row & 7)) * 8)];
        }
#pragma unroll
        for (int j = 0; j < 8; ++j) {
            int col = wc * 128 + j * 16 + l16;
            bfr[j] = *(const bf16x8*)&Bsb[col * 32 + ((quad ^ ((col >> 1) & 3)) * 8)];
        }
#pragma unroll
        for (int i = 0; i < 3; ++i)
#pragma unroll
            for (int j = 0; j < 8; ++j)
                acc[i][j] = __builtin_amdgcn_mfma_f32_16x16x32_bf16(
                    af[i], bfr[j], acc[i][j], 0, 0, 0);
    };

    if (t < 4 * BM) load_pair(dxyr[0], k4);
    SCHEDB;
    dma_phase(0, Bs0);
    SCHEDB;

#pragma unroll
    for (int cc = 0; cc < 6; ++cc) {
        SBAR;
        SCHEDB;
        VMCNT(4);
        SCHEDB;
        if (t < 4 * BM) {
            bf16x8 oa, ob;
#pragma unroll
            for (int q = 0; q < 2; ++q) {
                fx4 v0 = g0[q], v1 = g1[q];
                oa[q * 4 + 0] = (__bf16)(w0 * v0.x + w1 * v1.x);
                oa[q * 4 + 1] = (__bf16)(w0 * v0.y + w1 * v1.y);
                oa[q * 4 + 2] = (__bf16)(w0 * v0.z + w1 * v1.z);
                oa[q * 4 + 3] = (__bf16)(w0 * v0.w + w1 * v1.w);
            }
#pragma unroll
            for (int q = 0; q < 2; ++q) {
                fx4 v0 = g0[q + 2], v1 = g1[q + 2];
                ob[q * 4 + 0] = (__bf16)(w0 * v0.x + w1 * v1.x);
                ob[q * 4 + 1] = (__bf16)(w0 * v0.y + w1 * v1.y);
                ob[q * 4 + 2] = (__bf16)(w0 * v0.z + w1 * v1.z);
                ob[q * 4 + 3] = (__bf16)(w0 * v0.w + w1 * v1.w);
            }
            int g = 2 * k4;
            *(bf16x8*)&As[mloc * BK + ((g ^ (mloc & 7)) * 8)]       = oa;
            *(bf16x8*)&As[mloc * BK + (((g + 1) ^ (mloc & 7)) * 8)] = ob;
        }
        SCHEDB;
        dma_phase(2 * cc + 1, Bs1);
        SCHEDB;
        if (cc + 1 < 6 && t < 4 * BM)
            load_pair(dxyr[cc + 1], 4 * (cc + 1) + k4);
        SCHEDB;
        LGKMCNT0;
        SCHEDB;
        SBAR;
        SCHEDB;
        if (cc < 5) { if (wave < 6) { VMCNT(12); } else { VMCNT(4); } }
        else        { VMCNT(4); }
        SCHEDB;
        SBAR;
        SCHEDB;
        __builtin_amdgcn_s_setprio(1);
        mfma_phase(0, Bs0);
        __builtin_amdgcn_s_setprio(0);
        SCHEDB;
        if (cc < 5) { if (wave < 6) { VMCNT(8); } else { VMCNT(0); } }
        else        { VMCNT(0); }
        SCHEDB;
        SBAR;
        SCHEDB;
        if (cc < 5) dma_phase(2 * cc + 2, Bs0);
        SCHEDB;
        __builtin_amdgcn_s_setprio(1);
        mfma_phase(1, Bs1);
        __builtin_amdgcn_s_setprio(0);
        SCHEDB;
    }

#pragma unroll
    for (int j = 0; j < 8; ++j) {
        int col = wc * 128 + j * 16 + l16;
        float bj = bias[col];
#pragma unroll
        for (int i = 0; i < 3; ++i) {
            int rowb = m0 + wr * 48 + i * 16 + quad * 4;
#pragma unroll
            for (int r = 0; r < 4; ++r)
                out[(size_t)(rowb + r) * DOUT + col] = acc[i][j][r] + bj;
        }
    }
}

// ---------------------------------------------------------------------------
extern "C" void kernel_launch(void* const* d_in, const int* in_sizes, int n_in,
                              void* d_out, int out_size, void* d_ws, size_t ws_size,
                              hipStream_t stream)
{
    const float* x     = (const float*)d_in[0];
    const float* w_off = (const float*)d_in[1];
    const float* b_off = (const float*)d_in[2];
    const float* w_def = (const float*)d_in[3];
    const float* b_def = (const float*)d_in[4];
    float* out = (float*)d_out;

    char* ws = (char*)d_ws;
    __bf16* wdef_b = (__bf16*)ws;                 // 393,216 B
    __bf16* woff_b = (__bf16*)(ws + 393216);      //  36,864 B
    __bf16* A_ws   = (__bf16*)(ws + 430080);      // up to 37,748,736 B

    prep_kernel<<<768, 256, 0, stream>>>(w_off, w_def, woff_b, wdef_b);

    const size_t afull = (size_t)MROWS * CK * 2;  // 37.75 MB
    int S = -1;
    for (int s = 1; s <= 32; s <<= 1) {
        if (430080 + afull / s <= ws_size) { S = s; break; }
    }
    if (S > 0) {
        int rows = MROWS / S;                     // multiple of 96 and 64
        for (int c = 0; c < S; ++c) {
            int mb = c * rows;
            k1_gather<<<rows / BM, 384, 0, stream>>>(x, woff_b, b_off, A_ws, mb);
            k2_gemm<<<(rows / 64) * 4, 256, 0, stream>>>(A_ws, wdef_b, b_def, out, mb);
        }
    } else {
        gemm_fused<<<MROWS / BM, 512, 0, stream>>>(x, woff_b, b_off, wdef_b, b_def, out);
    }
}